// Round 11
// baseline (2649.786 us; speedup 1.0000x reference)
//
#include <hip/hip_runtime.h>
#include <hip/hip_bf16.h>
#include <stdint.h>

// GRU-D encoder, MI355X, round 11: barrier-free recurrence with
// fragment-layout interchange buffers.
// B=256, S=200, D=64, H=512, TD=8.
// XP[t,b,1536] precomputed -> recurrent GEMMs are K=512. Per rb (16 rows):
// 4 gate WGs (r+h+gamma; Ur/Uh/Wdg resident) + 2 z WGs (Uz resident).
// HDECB/RHB stored in MFMA A-panel layout so producers write contiguous 16B
// chunks and consumers load A-fragments DIRECTLY to registers (16B/lane
// coalesced) -- no LDS staging, no __syncthreads in the hot loop.
// 96 WGs, XCD-colocated. Pure busy polls, fuel-bounded (fail fast).

typedef unsigned short u16;
typedef unsigned int   u32;
typedef unsigned long long u64;
typedef short bfrag  __attribute__((ext_vector_type(8)));
typedef u16   u16x8  __attribute__((ext_vector_type(8)));
typedef float f32x4  __attribute__((ext_vector_type(4)));

#define NB 256
#define NS 200
#define ND 64
#define NH 512

#define MFMA(a,b,c) __builtin_amdgcn_mfma_f32_16x16x32_bf16((a),(b),(c),0,0,0)

union UQ { u16x8 h; bfrag s; u64 u[2]; uint4 q; };

__device__ __forceinline__ float b2f(u16 v){ union { float f; u32 u; } c; c.u = ((u32)v) << 16; return c.f; }
__device__ __forceinline__ u16 f2b(float f){ union { float f; u32 u; } c; c.f = f; u32 r = c.u + 0x7FFFu + ((c.u >> 16) & 1u); return (u16)(r >> 16); }
__device__ __forceinline__ float sigm(float x){ return 1.f / (1.f + __expf(-x)); }
__device__ __forceinline__ float tanh_f(float x){ return 1.f - 2.f / (1.f + __expf(2.f * x)); }

// agent-scope (coherence-point) ops for cross-WG data
__device__ __forceinline__ u64 cload64(const void* p){
  return __hip_atomic_load((const u64*)p, __ATOMIC_RELAXED, __HIP_MEMORY_SCOPE_AGENT);
}
__device__ __forceinline__ void cstore64(void* p, u64 v){
  __hip_atomic_store((u64*)p, v, __ATOMIC_RELAXED, __HIP_MEMORY_SCOPE_AGENT);
}
__device__ __forceinline__ u32 cload32(const u32* p){
  return __hip_atomic_load(p, __ATOMIC_RELAXED, __HIP_MEMORY_SCOPE_AGENT);
}
__device__ __forceinline__ void cstore32(u32* p, u32 v){
  __hip_atomic_store(p, v, __ATOMIC_RELAXED, __HIP_MEMORY_SCOPE_AGENT);
}
// lane-parallel busy poll, fuel-bounded (fail fast, no GPU hang)
__device__ __forceinline__ bool poll_ge(const u32* wp, u32 tgt){
  int fuel = 1 << 18;
  while (true) {
    u32 v = cload32(wp);
    if (__all(v >= tgt)) return true;
    if (--fuel == 0) return false;
  }
}
__device__ __forceinline__ bfrag ldfrag(const float* src){
  f32x4 lo = *(const f32x4*)src;
  f32x4 hi = *(const f32x4*)(src + 4);
  UQ z;
  z.h[0]=f2b(lo[0]); z.h[1]=f2b(lo[1]); z.h[2]=f2b(lo[2]); z.h[3]=f2b(lo[3]);
  z.h[4]=f2b(hi[0]); z.h[5]=f2b(hi[1]); z.h[6]=f2b(hi[2]); z.h[7]=f2b(hi[3]);
  return z.s;
}

// ---------------- setup kernels ----------------

__global__ void transpose_k(const float* __restrict__ Wout, float* __restrict__ WT){
  int i = blockIdx.x * 256 + threadIdx.x;
  if (i < 520 * 512) { int k = i >> 9, ho = i & 511; WT[i] = Wout[ho * 520 + k]; }
}

__global__ void mean1_k(const float* __restrict__ x, const float* __restrict__ mask,
                        float* __restrict__ PX, float* __restrict__ PM){
  int s = blockIdx.x, tid = threadIdx.x;
  __shared__ float lx[256], lm[256];
  float xa = 0.f, ma = 0.f;
  for (int i = tid; i < NB * ND; i += 256) {
    int b = i >> 6, d = i & 63;
    size_t ix = ((size_t)b * NS + s) * 64 + d;
    float m = mask[ix];
    xa += m * x[ix]; ma += m;
  }
  lx[tid] = xa; lm[tid] = ma;
  __syncthreads();
  if (tid < 64) {
    PX[(size_t)s * 64 + tid] = lx[tid] + lx[tid + 64] + lx[tid + 128] + lx[tid + 192];
    PM[(size_t)s * 64 + tid] = lm[tid] + lm[tid + 64] + lm[tid + 128] + lm[tid + 192];
  }
}

__global__ void mean2_k(const float* __restrict__ PX, const float* __restrict__ PM,
                        float* __restrict__ XMEAN){
  int d = threadIdx.x;
  float sx = 0.f, sm = 0.f;
  for (int s = 0; s < NS; ++s){ sx += PX[s * 64 + d]; sm += PM[s * 64 + d]; }
  XMEAN[d] = sx / fmaxf(sm, 1.f);
}

__global__ void prep_k(const float* __restrict__ x, const float* __restrict__ mask,
                       const float* __restrict__ tc, const float* __restrict__ wdgx,
                       const float* __restrict__ bdgx, const float* __restrict__ XMEAN,
                       u16* __restrict__ XHAT, u16* __restrict__ MASKB, u16* __restrict__ DELTA){
  int g = blockIdx.x * 256 + threadIdx.x;
  int b = g >> 6, d = g & 63;
  float xmean = XMEAN[d], wx = wdgx[d], bx = bdgx[d];
  float xl = 0.f, del = 0.f, tprev = 0.f, mprev = 1.f;
  for (int s = 0; s < NS; ++s){
    float tv = tc[b * NS + s];
    float dtv = (s == 0) ? 0.f : (tv - tprev);
    tprev = tv;
    del = dtv + (1.f - mprev) * del;
    size_t ix = ((size_t)b * NS + s) * 64 + d;
    float m = mask[ix], xv = x[ix];
    float gx = __expf(-fmaxf(0.f, wx * del + bx));
    float xh = m * xv + (1.f - m) * (gx * xl + (1.f - gx) * xmean);
    size_t ox = ((size_t)s * NB + b) * 64 + d;
    XHAT[ox] = f2b(xh); MASKB[ox] = f2b(m); DELTA[ox] = f2b(del);
    xl = m * xv + (1.f - m) * xl;
    mprev = m;
  }
}

// ---------------- XP precompute ----------------
__global__ void xpart_k(const float* __restrict__ Wm, const float* __restrict__ Vm,
                        const float* __restrict__ bv, const u16* __restrict__ XHAT,
                        const u16* __restrict__ MASKB, u16* __restrict__ XP){
  const int tid = threadIdx.x, lane = tid & 63, wid = tid >> 6;
  const int l16 = lane & 15, krow = lane >> 4, r4 = lane >> 2, cb = (lane & 3) * 8;
  const int chunk = blockIdx.x >> 1, p = blockIdx.x & 1;
  const int R0 = chunk * 128;
  const int wbase = p * 768 + wid * 192;
  __shared__ u16 panel[16 * 16 * 8];
  __shared__ float xb[4][16 * 35];
  float* xw = xb[wid];
  const f32x4 Z4 = {0.f, 0.f, 0.f, 0.f};

  bfrag BW[12][2], BV2[12][2];
  #pragma unroll
  for (int ct = 0; ct < 12; ++ct)
    #pragma unroll
    for (int kx = 0; kx < 2; ++kx) {
      BW[ct][kx]  = ldfrag(Wm + (size_t)(wbase + ct * 16 + l16) * 64 + kx * 32 + krow * 8);
      BV2[ct][kx] = ldfrag(Vm + (size_t)(wbase + ct * 16 + l16) * 64 + kx * 32 + krow * 8);
    }
  float bias6[6][8];
  #pragma unroll
  for (int grp = 0; grp < 6; ++grp)
    #pragma unroll
    for (int q = 0; q < 8; ++q) bias6[grp][q] = bv[wbase + grp * 32 + cb + q];

  for (int it = 0; it < 8; ++it) {
    const int R = R0 + it * 16;
    { const int kb = tid >> 4, row = tid & 15;
      const u16* sp = (kb < 8 ? XHAT : MASKB) + (size_t)(R + row) * 64 + (kb & 7) * 8;
      *(uint4*)&panel[(kb * 16 + row) * 8] = *(const uint4*)sp; }
    __syncthreads();
    u16* orow_ = XP + (size_t)(R + r4) * 1536 + wbase;
    #pragma unroll
    for (int grp = 0; grp < 6; ++grp) {
      f32x4 ac0 = Z4, ac1 = Z4;
      #pragma unroll
      for (int kx = 0; kx < 2; ++kx) {
        bfrag ax = *(const bfrag*)&panel[((kx * 4 + krow) * 16 + l16) * 8];
        ac0 = MFMA(ax, BW[grp*2][kx], ac0); ac1 = MFMA(ax, BW[grp*2+1][kx], ac1);
        bfrag am = *(const bfrag*)&panel[((8 + kx * 4 + krow) * 16 + l16) * 8];
        ac0 = MFMA(am, BV2[grp*2][kx], ac0); ac1 = MFMA(am, BV2[grp*2+1][kx], ac1);
      }
      #pragma unroll
      for (int j = 0; j < 4; ++j) { xw[(krow*4+j)*35 + l16] = ac0[j]; xw[(krow*4+j)*35 + 16 + l16] = ac1[j]; }
      UQ ov;
      #pragma unroll
      for (int q = 0; q < 8; ++q) ov.h[q] = f2b(xw[r4 * 35 + cb + q] + bias6[grp][q]);
      *(u64*)(orow_ + grp * 32 + cb) = ov.u[0];
      *(u64*)(orow_ + grp * 32 + cb + 4) = ov.u[1];
    }
    __syncthreads();
  }
}

// ---------------- persistent recurrent kernel ----------------
// grid = 96 WGs: lid = (bid&7)*12 + (bid>>3); rb = lid/6; role = lid%6.
// role 0..3: gate WG (wave owns 32 cols of r, h, gamma). role 4..5: z WG
// (wave owns 64 cols of z). HP/RP are A-panel-layout interchange buffers
// [rb][kb][row][8]. Flags per rb (stride 64): FH[16]@0, FR[16]@16, FZ[8]@32.
__global__ __launch_bounds__(256, 1) void grud_rnn(
    const float* __restrict__ Um, const float* __restrict__ Wdg, const float* __restrict__ bdg,
    const u16* __restrict__ XP, const u16* __restrict__ DELTA,
    u16* __restrict__ HP, u16* __restrict__ RP, u16* __restrict__ ZZB,
    u16* __restrict__ HALL, u32* __restrict__ flags)
{
  const int tid = threadIdx.x, lane = tid & 63, wid = tid >> 6, bid = blockIdx.x;
  const int lid = (bid & 7) * 12 + (bid >> 3);
  const int rb = lid / 6, role = lid % 6, m0 = rb * 16;
  const int l16 = lane & 15, krow = lane >> 4, r4 = lane >> 2, cb = (lane & 3) * 8;
  u32* FB = flags + rb * 64;
  u16* HPr = HP + rb * 8192;
  u16* RPr = RP + rb * 8192;

  __shared__ float xb[4][16 * 68];   // per-wave transpose scratch
  float* xw = xb[wid];
  const f32x4 Z4 = {0.f, 0.f, 0.f, 0.f};

  if (role < 4) {
    // ================= gate wave (fully autonomous) =================
    const int pw = role * 4 + wid;
    const int cw = role * 128 + wid * 32;
    const int slotp = ((cw + cb) >> 3) * 16 + r4;
    bfrag BR[16][2], BH[16][2], BG[2][2];
    #pragma unroll
    for (int kk = 0; kk < 16; ++kk) {
      const size_t ko = (size_t)(kk * 32 + krow * 8);
      #pragma unroll
      for (int t2 = 0; t2 < 2; ++t2) {
        BR[kk][t2] = ldfrag(Um + (size_t)(512  + cw + t2 * 16 + l16) * 512 + ko);
        BH[kk][t2] = ldfrag(Um + (size_t)(1024 + cw + t2 * 16 + l16) * 512 + ko);
      }
    }
    #pragma unroll
    for (int kk = 0; kk < 2; ++kk)
      #pragma unroll
      for (int t2 = 0; t2 < 2; ++t2)
        BG[kk][t2] = ldfrag(Wdg + (size_t)(cw + t2 * 16 + l16) * 64 + kk * 32 + krow * 8);
    float gb8[8];
    #pragma unroll
    for (int q = 0; q < 8; ++q) gb8[q] = bdg[cw + cb + q];

    UQ hd_; hd_.u[0] = 0; hd_.u[1] = 0;   // own h_dec strip, kept in regs

    for (int t = 0; t < NS; ++t) {
      const int tn = (t + 1 < NS) ? t + 1 : NS - 1;
      // static prefetch: XP strips (plain cached) + delta(t+1) frags
      const u16* xp = XP + ((size_t)t * NB + m0 + r4) * 1536 + cw + cb;
      u64 xr0 = *(const u64*)(xp + 512),  xr1 = *(const u64*)(xp + 516);
      u64 xh0 = *(const u64*)(xp + 1024), xh1 = *(const u64*)(xp + 1028);
      const u16* dpp = DELTA + ((size_t)tn * NB + m0 + l16) * 64 + krow * 8;
      UQ DA[2];
      DA[0].u[0] = *(const u64*)(dpp);      DA[0].u[1] = *(const u64*)(dpp + 4);
      DA[1].u[0] = *(const u64*)(dpp + 32); DA[1].u[1] = *(const u64*)(dpp + 36);
      // ---- hop 1: h_dec(t) A-frags direct to registers ----
      if (t > 0) { if (!poll_ge(FB + (lane & 15), (u32)t)) return; }
      UQ A[16];
      if (t > 0) {
        #pragma unroll
        for (int kk = 0; kk < 16; ++kk) {
          const u16* p = HPr + (size_t)(kk * 64 + krow * 16 + l16) * 8;
          A[kk].u[0] = cload64(p); A[kk].u[1] = cload64(p + 4);
        }
      } else {
        #pragma unroll
        for (int kk = 0; kk < 16; ++kk) { A[kk].u[0] = 0; A[kk].u[1] = 0; }
      }
      // r GEMM
      f32x4 aR0 = Z4, aR1 = Z4;
      #pragma unroll
      for (int kk = 0; kk < 16; ++kk) {
        aR0 = MFMA(A[kk].s, BR[kk][0], aR0); aR1 = MFMA(A[kk].s, BR[kk][1], aR1);
      }
      #pragma unroll
      for (int j = 0; j < 4; ++j) { xw[(krow*4+j)*68 + l16] = aR0[j]; xw[(krow*4+j)*68 + 16 + l16] = aR1[j]; }
      UQ xr_; xr_.u[0] = xr0; xr_.u[1] = xr1;
      UQ rh_;
      #pragma unroll
      for (int q = 0; q < 8; ++q) {
        float rv = sigm(b2f(xr_.h[q]) + xw[r4 * 68 + cb + q]);
        rh_.h[q] = f2b(rv * b2f(hd_.h[q]));
      }
      { u16* rdst = RPr + (size_t)slotp * 8;
        cstore64(rdst, rh_.u[0]); cstore64(rdst + 4, rh_.u[1]); }
      asm volatile("s_waitcnt vmcnt(0)" ::: "memory");
      if (lane == 0) cstore32(FB + 16 + pw, (u32)(t + 1));
      // gamma GEMM (static delta; fills part of the rh window)
      f32x4 g0 = Z4, g1 = Z4;
      #pragma unroll
      for (int kk = 0; kk < 2; ++kk) {
        g0 = MFMA(DA[kk].s, BG[kk][0], g0); g1 = MFMA(DA[kk].s, BG[kk][1], g1);
      }
      #pragma unroll
      for (int j = 0; j < 4; ++j) { xw[(krow*4+j)*68 + l16] = g0[j]; xw[(krow*4+j)*68 + 16 + l16] = g1[j]; }
      float gm8[8];
      #pragma unroll
      for (int q = 0; q < 8; ++q)
        gm8[q] = __expf(-fmaxf(0.f, xw[r4 * 68 + cb + q] + gb8[q]));
      // ---- hop 2: rh + z ready ----
      { const u32* wp; u32 tg = (u32)(t + 1);
        if (lane < 16)      wp = FB + 16 + lane;
        else if (lane < 24) wp = FB + 32 + (lane - 16);
        else                wp = FB + 16;
        if (!poll_ge(wp, tg)) return; }
      u64 zz0 = cload64(ZZB + (size_t)(m0 + r4) * 512 + cw + cb);
      u64 zz1 = cload64(ZZB + (size_t)(m0 + r4) * 512 + cw + cb + 4);
      #pragma unroll
      for (int kk = 0; kk < 16; ++kk) {
        const u16* p = RPr + (size_t)(kk * 64 + krow * 16 + l16) * 8;
        A[kk].u[0] = cload64(p); A[kk].u[1] = cload64(p + 4);
      }
      f32x4 aH0 = Z4, aH1 = Z4;
      #pragma unroll
      for (int kk = 0; kk < 16; ++kk) {
        aH0 = MFMA(A[kk].s, BH[kk][0], aH0); aH1 = MFMA(A[kk].s, BH[kk][1], aH1);
      }
      #pragma unroll
      for (int j = 0; j < 4; ++j) { xw[(krow*4+j)*68 + l16] = aH0[j]; xw[(krow*4+j)*68 + 16 + l16] = aH1[j]; }
      UQ xh_; xh_.u[0] = xh0; xh_.u[1] = xh1;
      UQ zz_; zz_.u[0] = zz0; zz_.u[1] = zz1;
      UQ hw_, hdn_;
      #pragma unroll
      for (int q = 0; q < 8; ++q) {
        float til = tanh_f(b2f(xh_.h[q]) + xw[r4 * 68 + cb + q]);
        float z = b2f(zz_.h[q]);
        float hn = (1.f - z) * b2f(hd_.h[q]) + z * til;
        hw_.h[q] = f2b(hn);
        hdn_.h[q] = f2b(gm8[q] * hn);
      }
      if (t + 1 < NS) {
        u16* hdst = HPr + (size_t)slotp * 8;
        cstore64(hdst, hdn_.u[0]); cstore64(hdst + 4, hdn_.u[1]);
      }
      asm volatile("s_waitcnt vmcnt(0)" ::: "memory");
      if (lane == 0) cstore32(FB + 0 + pw, (u32)(t + 1));
      hd_ = hdn_;
      // HALL store off critical path (row-major, plain)
      u16* hp = HALL + ((size_t)t * NB + m0 + r4) * 512 + cw + cb;
      *(u64*)hp = hw_.u[0]; *(u64*)(hp + 4) = hw_.u[1];
    }
  } else {
    // ================= z wave (fully autonomous) =================
    const int zi = role - 4;
    const int pz = zi * 4 + wid;
    const int zc = zi * 256 + wid * 64;     // wave's 64 z-cols
    const int cb2 = (lane & 3) * 16;
    bfrag BZ[16][4];                        // 64 frags = 256 regs, resident
    #pragma unroll
    for (int kk = 0; kk < 16; ++kk)
      #pragma unroll
      for (int ct = 0; ct < 4; ++ct)
        BZ[kk][ct] = ldfrag(Um + (size_t)(zc + ct * 16 + l16) * 512 + kk * 32 + krow * 8);

    for (int t = 0; t < NS; ++t) {
      const u16* xp = XP + ((size_t)t * NB + m0 + r4) * 1536 + zc + cb2;
      u64 xz[4];
      #pragma unroll
      for (int c = 0; c < 4; ++c) xz[c] = *(const u64*)(xp + c * 4);
      if (t > 0) { if (!poll_ge(FB + (lane & 15), (u32)t)) return; }
      UQ A[16];
      if (t > 0) {
        #pragma unroll
        for (int kk = 0; kk < 16; ++kk) {
          const u16* p = HP + (size_t)rb * 8192 + (size_t)(kk * 64 + krow * 16 + l16) * 8;
          A[kk].u[0] = cload64(p); A[kk].u[1] = cload64(p + 4);
        }
      } else {
        #pragma unroll
        for (int kk = 0; kk < 16; ++kk) { A[kk].u[0] = 0; A[kk].u[1] = 0; }
      }
      f32x4 acc[4] = {Z4, Z4, Z4, Z4};
      #pragma unroll
      for (int kk = 0; kk < 16; ++kk) {
        #pragma unroll
        for (int ct = 0; ct < 4; ++ct) acc[ct] = MFMA(A[kk].s, BZ[kk][ct], acc[ct]);
      }
      #pragma unroll
      for (int ct = 0; ct < 4; ++ct)
        #pragma unroll
        for (int j = 0; j < 4; ++j)
          xw[(krow * 4 + j) * 68 + ct * 16 + l16] = acc[ct][j];
      UQ z0, z1;
      #pragma unroll
      for (int q = 0; q < 8; ++q) {
        UQ xzq; xzq.u[0] = xz[q >> 2];   // not used this way; recompute below
      }
      // compute z = sigm(xz + s) for 16 cols
      float s16[16];
      #pragma unroll
      for (int q = 0; q < 16; ++q) s16[q] = xw[r4 * 68 + cb2 + q];
      UQ zo[2];
      #pragma unroll
      for (int c = 0; c < 2; ++c) {
        UQ xa; xa.u[0] = xz[c * 2]; xa.u[1] = xz[c * 2 + 1];
        UQ ov;
        #pragma unroll
        for (int q = 0; q < 8; ++q) ov.h[q] = f2b(sigm(b2f(xa.h[q]) + s16[c * 8 + q]));
        zo[c] = ov;
      }
      u16* zdst = ZZB + (size_t)(m0 + r4) * 512 + zc + cb2;
      cstore64(zdst, zo[0].u[0]); cstore64(zdst + 4, zo[0].u[1]);
      cstore64(zdst + 8, zo[1].u[0]); cstore64(zdst + 12, zo[1].u[1]);
      asm volatile("s_waitcnt vmcnt(0)" ::: "memory");
      if (lane == 0) cstore32(FB + 32 + pz, (u32)(t + 1));
    }
  }
}

// ---------------- post kernels ----------------

__global__ void attn_k(const u16* __restrict__ HALL, const float* __restrict__ av,
                       float* __restrict__ ATTN){
  const int b = blockIdx.x, tid = threadIdx.x, lane = tid & 63, wid = tid >> 6;
  __shared__ float avs[512], wgt[256], red[8];
  for (int i = tid; i < 512; i += 256) avs[i] = av[i];
  __syncthreads();
  float val = -3.0e38f;
  if (tid < NS) {
    const u16* hp = HALL + ((size_t)tid * NB + b) * 512;
    float acc = 0.f;
    for (int h = 0; h < 512; h += 8) {
      UQ w; w.q = *(const uint4*)(hp + h);
      #pragma unroll
      for (int j = 0; j < 8; ++j) acc += b2f(w.h[j]) * avs[h + j];
    }
    val = acc * 0.04419417382415922f;   // 1/sqrt(512)
  }
  float m = val;
  #pragma unroll
  for (int off = 32; off; off >>= 1) m = fmaxf(m, __shfl_xor(m, off, 64));
  if (lane == 0) red[wid] = m;
  __syncthreads();
  m = fmaxf(fmaxf(red[0], red[1]), fmaxf(red[2], red[3]));
  float e = (tid < NS) ? __expf(val - m) : 0.f;
  float sum = e;
  #pragma unroll
  for (int off = 32; off; off >>= 1) sum += __shfl_xor(sum, off, 64);
  if (lane == 0) red[4 + wid] = sum;
  __syncthreads();
  const float ssum = red[4] + red[5] + red[6] + red[7];
  wgt[tid] = e / ssum;
  __syncthreads();
  float a0 = 0.f, a1 = 0.f;
  const int h0 = tid * 2;
  for (int s = 0; s < NS; ++s) {
    float w = wgt[s];
    u32 pr = *(const u32*)(HALL + ((size_t)s * NB + b) * 512 + h0);
    a0 += w * b2f((u16)(pr & 0xFFFFu));
    a1 += w * b2f((u16)(pr >> 16));
  }
  ATTN[(size_t)b * 512 + h0] = a0;
  ATTN[(size_t)b * 512 + h0 + 1] = a1;
}

__global__ void out_k(const float* __restrict__ ATTN, const float* __restrict__ Ain,
                      const float* __restrict__ WT, const float* __restrict__ bout,
                      float* __restrict__ OUT){
  const int g = blockIdx.x, tid = threadIdx.x;
  __shared__ float ah[4][520];
  for (int i = tid; i < 4 * 520; i += 256) {
    int bb = i / 520, k = i % 520;
    int b = g * 4 + bb;
    ah[bb][k] = (k < 512) ? ATTN[(size_t)b * 512 + k] : Ain[b * 8 + (k - 512)];
  }
  __syncthreads();
  #pragma unroll
  for (int part = 0; part < 2; ++part) {
    const int ho = part * 256 + tid;
    float a0 = bout[ho], a1 = a0, a2 = a0, a3 = a0;
    for (int k = 0; k < 520; ++k) {
      float w = WT[(size_t)k * 512 + ho];
      a0 += ah[0][k] * w; a1 += ah[1][k] * w; a2 += ah[2][k] * w; a3 += ah[3][k] * w;
    }
    OUT[(size_t)(g * 4 + 0) * 512 + ho] = a0;
    OUT[(size_t)(g * 4 + 1) * 512 + ho] = a1;
    OUT[(size_t)(g * 4 + 2) * 512 + ho] = a2;
    OUT[(size_t)(g * 4 + 3) * 512 + ho] = a3;
  }
}

// ---------------- host ----------------

extern "C" void kernel_launch(void* const* d_in, const int* in_sizes, int n_in,
                              void* d_out, int out_size, void* d_ws, size_t ws_size,
                              hipStream_t stream) {
  (void)in_sizes; (void)n_in; (void)out_size; (void)ws_size;
  const float* x    = (const float*)d_in[0];
  const float* a_in = (const float*)d_in[1];
  const float* tc   = (const float*)d_in[2];
  const float* mask = (const float*)d_in[3];
  const float* wdgx = (const float*)d_in[4];
  const float* bdgx = (const float*)d_in[5];
  const float* Wdgh = (const float*)d_in[6];
  const float* bdgh = (const float*)d_in[7];
  const float* Wm   = (const float*)d_in[8];
  const float* Um   = (const float*)d_in[9];
  const float* Vm   = (const float*)d_in[10];
  const float* bvv  = (const float*)d_in[11];
  const float* attv = (const float*)d_in[12];
  const float* Wout = (const float*)d_in[13];
  const float* bout = (const float*)d_in[14];

  char* ws = (char*)d_ws;
  size_t o = 0;
  auto al = [&](size_t sz) { size_t r = o; o += (sz + 255) & ~(size_t)255; return r; };
  u32*   flags = (u32*)  (ws + al(16 * 64 * 4));
  float* XMEAN = (float*)(ws + al(256));
  float* PX    = (float*)(ws + al((size_t)NS * 64 * 4));
  float* PM    = (float*)(ws + al((size_t)NS * 64 * 4));
  u16*   XHAT  = (u16*)  (ws + al((size_t)NS * NB * 64 * 2));
  u16*   MASKB = (u16*)  (ws + al((size_t)NS * NB * 64 * 2));
  u16*   DELTA = (u16*)  (ws + al((size_t)NS * NB * 64 * 2));
  u16*   HP    = (u16*)  (ws + al((size_t)16 * 8192 * 2));
  u16*   RP    = (u16*)  (ws + al((size_t)16 * 8192 * 2));
  u16*   ZZB   = (u16*)  (ws + al((size_t)NB * NH * 2));
  u16*   XP    = (u16*)  (ws + al((size_t)NS * NB * 1536 * 2));   // 157 MB
  u16*   HALL  = (u16*)  (ws + al((size_t)NS * NB * NH * 2));     // 52 MB
  float* ATTN  = (float*)(ws + al((size_t)NB * NH * 4));
  float* WT    = (float*)(ws + al((size_t)520 * 512 * 4));

  hipMemsetAsync(flags, 0, 16 * 64 * 4, stream);

  transpose_k<<<(520 * 512 + 255) / 256, 256, 0, stream>>>(Wout, WT);
  mean1_k<<<NS, 256, 0, stream>>>(x, mask, PX, PM);
  mean2_k<<<1, 64, 0, stream>>>(PX, PM, XMEAN);
  prep_k<<<NB * ND / 256, 256, 0, stream>>>(x, mask, tc, wdgx, bdgx, XMEAN, XHAT, MASKB, DELTA);
  xpart_k<<<800, 256, 0, stream>>>(Wm, Vm, bvv, XHAT, MASKB, XP);
  grud_rnn<<<96, 256, 0, stream>>>(Um, Wdgh, bdgh, XP, DELTA, HP, RP, ZZB, HALL, flags);
  attn_k<<<NB, 256, 0, stream>>>(HALL, attv, ATTN);
  out_k<<<64, 256, 0, stream>>>(ATTN, a_in, WT, bout, (float*)d_out);
}

// Round 12
// 1871.745 us; speedup vs baseline: 1.4157x; 1.4157x over previous
//
#include <hip/hip_runtime.h>
#include <hip/hip_bf16.h>
#include <stdint.h>

// GRU-D encoder, MI355X, round 12.
// B=256, S=200, D=64, H=512, TD=8.
// Recurrence = round 10's proven structure (16 rb x 4 gate WGs, K=512 GEMMs
// on precomputed XP, LDS-staged hops, 2 polls/step). Changes this round:
//  - xpart_k: LDS-staged row-contiguous writes (1536B runs) + launch_bounds
//  - HALL stored [b][s][h] so attn_k reads are coalesced
//  - attn_k rewritten: coalesced row-dot scores + coalesced weighted sum

typedef unsigned short u16;
typedef unsigned int   u32;
typedef unsigned long long u64;
typedef short bfrag  __attribute__((ext_vector_type(8)));
typedef u16   u16x8  __attribute__((ext_vector_type(8)));
typedef float f32x4  __attribute__((ext_vector_type(4)));

#define NB 256
#define NS 200
#define ND 64
#define NH 512

#define MFMA(a,b,c) __builtin_amdgcn_mfma_f32_16x16x32_bf16((a),(b),(c),0,0,0)

union UQ { u16x8 h; bfrag s; u64 u[2]; uint4 q; };

__device__ __forceinline__ float b2f(u16 v){ union { float f; u32 u; } c; c.u = ((u32)v) << 16; return c.f; }
__device__ __forceinline__ u16 f2b(float f){ union { float f; u32 u; } c; c.f = f; u32 r = c.u + 0x7FFFu + ((c.u >> 16) & 1u); return (u16)(r >> 16); }
__device__ __forceinline__ float sigm(float x){ return 1.f / (1.f + __expf(-x)); }
__device__ __forceinline__ float tanh_f(float x){ return 1.f - 2.f / (1.f + __expf(2.f * x)); }

// agent-scope (coherence-point) ops for intra-kernel cross-WG data
__device__ __forceinline__ u64 cload64(const void* p){
  return __hip_atomic_load((const u64*)p, __ATOMIC_RELAXED, __HIP_MEMORY_SCOPE_AGENT);
}
__device__ __forceinline__ void cstore64(void* p, u64 v){
  __hip_atomic_store((u64*)p, v, __ATOMIC_RELAXED, __HIP_MEMORY_SCOPE_AGENT);
}
__device__ __forceinline__ u32 cload32(const u32* p){
  return __hip_atomic_load(p, __ATOMIC_RELAXED, __HIP_MEMORY_SCOPE_AGENT);
}
__device__ __forceinline__ void cstore32(u32* p, u32 v){
  __hip_atomic_store(p, v, __ATOMIC_RELAXED, __HIP_MEMORY_SCOPE_AGENT);
}
// lane-parallel poll with backoff, fuel-bounded (fail fast, no GPU hang)
__device__ __forceinline__ bool poll_ge(const u32* wp, u32 tgt){
  int fuel = 1 << 19;
  while (true) {
    u32 v = cload32(wp);
    if (__all(v >= tgt)) return true;
    __builtin_amdgcn_s_sleep(1);
    if (--fuel == 0) return false;
  }
}
__device__ __forceinline__ bfrag ldfrag(const float* src){
  f32x4 lo = *(const f32x4*)src;
  f32x4 hi = *(const f32x4*)(src + 4);
  UQ z;
  z.h[0]=f2b(lo[0]); z.h[1]=f2b(lo[1]); z.h[2]=f2b(lo[2]); z.h[3]=f2b(lo[3]);
  z.h[4]=f2b(hi[0]); z.h[5]=f2b(hi[1]); z.h[6]=f2b(hi[2]); z.h[7]=f2b(hi[3]);
  return z.s;
}
// cooperative coalesced staging of a [16][512] bf16 block into an A-panel
__device__ __forceinline__ void stage_bf16(u16* dst, const u16* src, int tid, bool zero){
  const int row = tid >> 4, sc = (tid & 15) * 32;
  u16* dp = &dst[((sc >> 3) * 16 + row) * 8];
  if (!zero) {
    const u16* hs = src + (size_t)row * 512 + sc;
    u64 a0 = cload64(hs),      a1 = cload64(hs + 4),  a2 = cload64(hs + 8),  a3 = cload64(hs + 12);
    u64 a4 = cload64(hs + 16), a5 = cload64(hs + 20), a6 = cload64(hs + 24), a7 = cload64(hs + 28);
    *(u64*)(dp)       = a0; *(u64*)(dp + 4)   = a1;
    *(u64*)(dp + 128) = a2; *(u64*)(dp + 132) = a3;
    *(u64*)(dp + 256) = a4; *(u64*)(dp + 260) = a5;
    *(u64*)(dp + 384) = a6; *(u64*)(dp + 388) = a7;
  } else {
    *(u64*)(dp)       = 0; *(u64*)(dp + 4)   = 0;
    *(u64*)(dp + 128) = 0; *(u64*)(dp + 132) = 0;
    *(u64*)(dp + 256) = 0; *(u64*)(dp + 260) = 0;
    *(u64*)(dp + 384) = 0; *(u64*)(dp + 388) = 0;
  }
}

// ---------------- setup kernels ----------------

__global__ void transpose_k(const float* __restrict__ Wout, float* __restrict__ WT){
  int i = blockIdx.x * 256 + threadIdx.x;
  if (i < 520 * 512) { int k = i >> 9, ho = i & 511; WT[i] = Wout[ho * 520 + k]; }
}

__global__ void mean1_k(const float* __restrict__ x, const float* __restrict__ mask,
                        float* __restrict__ PX, float* __restrict__ PM){
  int s = blockIdx.x, tid = threadIdx.x;
  __shared__ float lx[256], lm[256];
  float xa = 0.f, ma = 0.f;
  for (int i = tid; i < NB * ND; i += 256) {
    int b = i >> 6, d = i & 63;
    size_t ix = ((size_t)b * NS + s) * 64 + d;
    float m = mask[ix];
    xa += m * x[ix]; ma += m;
  }
  lx[tid] = xa; lm[tid] = ma;
  __syncthreads();
  if (tid < 64) {
    PX[(size_t)s * 64 + tid] = lx[tid] + lx[tid + 64] + lx[tid + 128] + lx[tid + 192];
    PM[(size_t)s * 64 + tid] = lm[tid] + lm[tid + 64] + lm[tid + 128] + lm[tid + 192];
  }
}

__global__ void mean2_k(const float* __restrict__ PX, const float* __restrict__ PM,
                        float* __restrict__ XMEAN){
  int d = threadIdx.x;
  float sx = 0.f, sm = 0.f;
  for (int s = 0; s < NS; ++s){ sx += PX[s * 64 + d]; sm += PM[s * 64 + d]; }
  XMEAN[d] = sx / fmaxf(sm, 1.f);
}

__global__ void prep_k(const float* __restrict__ x, const float* __restrict__ mask,
                       const float* __restrict__ tc, const float* __restrict__ wdgx,
                       const float* __restrict__ bdgx, const float* __restrict__ XMEAN,
                       u16* __restrict__ XHAT, u16* __restrict__ MASKB, u16* __restrict__ DELTA){
  int g = blockIdx.x * 256 + threadIdx.x;
  int b = g >> 6, d = g & 63;
  float xmean = XMEAN[d], wx = wdgx[d], bx = bdgx[d];
  float xl = 0.f, del = 0.f, tprev = 0.f, mprev = 1.f;
  for (int s = 0; s < NS; ++s){
    float tv = tc[b * NS + s];
    float dtv = (s == 0) ? 0.f : (tv - tprev);
    tprev = tv;
    del = dtv + (1.f - mprev) * del;
    size_t ix = ((size_t)b * NS + s) * 64 + d;
    float m = mask[ix], xv = x[ix];
    float gx = __expf(-fmaxf(0.f, wx * del + bx));
    float xh = m * xv + (1.f - m) * (gx * xl + (1.f - gx) * xmean);
    size_t ox = ((size_t)s * NB + b) * 64 + d;
    XHAT[ox] = f2b(xh); MASKB[ox] = f2b(m); DELTA[ox] = f2b(del);
    xl = m * xv + (1.f - m) * xl;
    mprev = m;
  }
}

// ---------------- XP precompute ----------------
// XP[row][1536] = [x_hat|m](row) @ [W|V]^T + b for all 51200 rows.
// LDS-staged epilogue -> row-contiguous 1536B write runs (full-line HBM writes).
__global__ __launch_bounds__(256, 1) void xpart_k(
    const float* __restrict__ Wm, const float* __restrict__ Vm,
    const float* __restrict__ bv, const u16* __restrict__ XHAT,
    const u16* __restrict__ MASKB, u16* __restrict__ XP){
  const int tid = threadIdx.x, lane = tid & 63, wid = tid >> 6;
  const int l16 = lane & 15, krow = lane >> 4, r4 = lane >> 2, cb = (lane & 3) * 8;
  const int chunk = blockIdx.x >> 1, p = blockIdx.x & 1;
  const int R0 = chunk * 128;
  const int wbasel = wid * 192;            // local col base within this half
  const int wbaseg = p * 768 + wbasel;     // global col base
  __shared__ u16 panel[16 * 16 * 8];
  __shared__ u16 outs[16][768];            // staged output (24 KB)
  __shared__ float xb[4][16 * 35];
  float* xw = xb[wid];
  const f32x4 Z4 = {0.f, 0.f, 0.f, 0.f};

  bfrag BW[12][2], BV2[12][2];
  #pragma unroll
  for (int ct = 0; ct < 12; ++ct)
    #pragma unroll
    for (int kx = 0; kx < 2; ++kx) {
      BW[ct][kx]  = ldfrag(Wm + (size_t)(wbaseg + ct * 16 + l16) * 64 + kx * 32 + krow * 8);
      BV2[ct][kx] = ldfrag(Vm + (size_t)(wbaseg + ct * 16 + l16) * 64 + kx * 32 + krow * 8);
    }
  float bias6[6][8];
  #pragma unroll
  for (int grp = 0; grp < 6; ++grp)
    #pragma unroll
    for (int q = 0; q < 8; ++q) bias6[grp][q] = bv[wbaseg + grp * 32 + cb + q];

  for (int it = 0; it < 8; ++it) {
    const int R = R0 + it * 16;
    { const int kb = tid >> 4, row = tid & 15;
      const u16* sp = (kb < 8 ? XHAT : MASKB) + (size_t)(R + row) * 64 + (kb & 7) * 8;
      *(uint4*)&panel[(kb * 16 + row) * 8] = *(const uint4*)sp; }
    __syncthreads();
    #pragma unroll
    for (int grp = 0; grp < 6; ++grp) {
      f32x4 ac0 = Z4, ac1 = Z4;
      #pragma unroll
      for (int kx = 0; kx < 2; ++kx) {
        bfrag ax = *(const bfrag*)&panel[((kx * 4 + krow) * 16 + l16) * 8];
        ac0 = MFMA(ax, BW[grp*2][kx], ac0); ac1 = MFMA(ax, BW[grp*2+1][kx], ac1);
        bfrag am = *(const bfrag*)&panel[((8 + kx * 4 + krow) * 16 + l16) * 8];
        ac0 = MFMA(am, BV2[grp*2][kx], ac0); ac1 = MFMA(am, BV2[grp*2+1][kx], ac1);
      }
      #pragma unroll
      for (int j = 0; j < 4; ++j) { xw[(krow*4+j)*35 + l16] = ac0[j]; xw[(krow*4+j)*35 + 16 + l16] = ac1[j]; }
      UQ ov;
      #pragma unroll
      for (int q = 0; q < 8; ++q) ov.h[q] = f2b(xw[r4 * 35 + cb + q] + bias6[grp][q]);
      *(u64*)&outs[r4][wbasel + grp * 32 + cb] = ov.u[0];
      *(u64*)&outs[r4][wbasel + grp * 32 + cb + 4] = ov.u[1];
    }
    __syncthreads();
    // cooperative coalesced write: 16 rows x 96 chunks of 16B (1536B runs)
    for (int c = tid; c < 16 * 96; c += 256) {
      const int row = c / 96, ch = c % 96;
      *(uint4*)(XP + (size_t)(R + row) * 1536 + p * 768 + ch * 8) =
          *(const uint4*)&outs[row][ch * 8];
    }
    __syncthreads();
  }
}

// ---------------- persistent recurrent kernel (= round 10) ----------------
// grid = 64 WGs (16 rb x 4 gate WGs), 256 threads (4 waves).
// XCD-colocating map: lid = (bid&7)*8 + (bid>>3); rb = lid>>2; g = lid&3.
// Flags per rb (stride 32 u32): FH[16]@0, FR[16]@16.
__global__ __launch_bounds__(256, 1) void grud_rnn(
    const float* __restrict__ Um, const float* __restrict__ Wdg, const float* __restrict__ bdg,
    const u16* __restrict__ XP, const u16* __restrict__ DELTA,
    u16* __restrict__ HDECB, u16* __restrict__ RHB, u16* __restrict__ HALL,
    u32* __restrict__ flags)
{
  const int tid = threadIdx.x, lane = tid & 63, wid = tid >> 6, bid = blockIdx.x;
  const int lid = (bid & 7) * 8 + (bid >> 3);
  const int rb = lid >> 2, g = lid & 3, m0 = rb * 16;
  const int l16 = lane & 15, krow = lane >> 4, r4 = lane >> 2, cb = (lane & 3) * 8;
  const int pw = g * 4 + wid;
  const int cw = g * 128 + wid * 32;
  u32* FB = flags + rb * 32;

  __shared__ u16 hpan[64 * 16 * 8];
  __shared__ u16 rpan[64 * 16 * 8];
  __shared__ u16 dpan[8 * 16 * 8];
  __shared__ float xb[4][16 * 34];
  __shared__ int s_ab;
  float* xw = xb[wid];
  const f32x4 Z4 = {0.f, 0.f, 0.f, 0.f};
  if (tid == 0) s_ab = 0;
  __syncthreads();

  bfrag BZ[16][2], BR[16][2], BH[16][2], BG[2][2];
  #pragma unroll
  for (int kk = 0; kk < 16; ++kk) {
    const size_t ko = (size_t)(kk * 32 + krow * 8);
    #pragma unroll
    for (int t2 = 0; t2 < 2; ++t2) {
      BZ[kk][t2] = ldfrag(Um + (size_t)(       cw + t2 * 16 + l16) * 512 + ko);
      BR[kk][t2] = ldfrag(Um + (size_t)(512  + cw + t2 * 16 + l16) * 512 + ko);
      BH[kk][t2] = ldfrag(Um + (size_t)(1024 + cw + t2 * 16 + l16) * 512 + ko);
    }
  }
  #pragma unroll
  for (int kk = 0; kk < 2; ++kk)
    #pragma unroll
    for (int t2 = 0; t2 < 2; ++t2)
      BG[kk][t2] = ldfrag(Wdg + (size_t)(cw + t2 * 16 + l16) * 64 + kk * 32 + krow * 8);
  float gb8[8];
  #pragma unroll
  for (int q = 0; q < 8; ++q) gb8[q] = bdg[cw + cb + q];

  const int slot = ((cw + cb) >> 3) * 16 + r4;

  for (int t = 0; t < NS; ++t) {
    const int tn = (t + 1 < NS) ? t + 1 : NS - 1;
    const u16* xp = XP + ((size_t)t * NB + m0 + r4) * 1536 + cw + cb;
    u64 xz0 = *(const u64*)(xp),        xz1 = *(const u64*)(xp + 4);
    u64 xr0 = *(const u64*)(xp + 512),  xr1 = *(const u64*)(xp + 516);
    u64 xh0 = *(const u64*)(xp + 1024), xh1 = *(const u64*)(xp + 1028);
    if (tid < 128) {
      const int kb = tid >> 4, row = tid & 15;
      const u16* sp = DELTA + ((size_t)tn * NB + m0 + row) * 64 + kb * 8;
      *(uint4*)&dpan[(kb * 16 + row) * 8] = *(const uint4*)sp;
    }
    // ---- hop 1: wait h_dec(t) ----
    if (wid == 0 && t > 0) { if (!poll_ge(FB + (lane & 15), (u32)t)) s_ab = 1; }
    __syncthreads();
    if (s_ab) break;
    stage_bf16(hpan, HDECB + (size_t)m0 * 512, tid, t == 0);
    __syncthreads();
    // ---- r GEMM (K=512) ----
    f32x4 aR0 = Z4, aR1 = Z4;
    #pragma unroll
    for (int kk = 0; kk < 16; ++kk) {
      bfrag a = *(const bfrag*)&hpan[((kk * 4 + krow) * 16 + l16) * 8];
      aR0 = MFMA(a, BR[kk][0], aR0); aR1 = MFMA(a, BR[kk][1], aR1);
    }
    #pragma unroll
    for (int j = 0; j < 4; ++j) { xw[(krow*4+j)*34 + l16] = aR0[j]; xw[(krow*4+j)*34 + 16 + l16] = aR1[j]; }
    UQ hd_; hd_.h = *(const u16x8*)&hpan[slot * 8];
    UQ xr_; xr_.u[0] = xr0; xr_.u[1] = xr1;
    UQ rh_;
    #pragma unroll
    for (int q = 0; q < 8; ++q) {
      float rv = sigm(b2f(xr_.h[q]) + xw[r4 * 34 + cb + q]);
      rh_.h[q] = f2b(rv * b2f(hd_.h[q]));
    }
    u16* rdst = RHB + (size_t)(m0 + r4) * 512 + cw + cb;
    cstore64(rdst, rh_.u[0]); cstore64(rdst + 4, rh_.u[1]);
    asm volatile("s_waitcnt vmcnt(0)" ::: "memory");
    if (lane == 0) cstore32(FB + 16 + pw, (u32)(t + 1));
    // ---- z GEMM + gamma GEMM fill the rh round-trip window ----
    f32x4 aZ0 = Z4, aZ1 = Z4;
    #pragma unroll
    for (int kk = 0; kk < 16; ++kk) {
      bfrag a = *(const bfrag*)&hpan[((kk * 4 + krow) * 16 + l16) * 8];
      aZ0 = MFMA(a, BZ[kk][0], aZ0); aZ1 = MFMA(a, BZ[kk][1], aZ1);
    }
    #pragma unroll
    for (int j = 0; j < 4; ++j) { xw[(krow*4+j)*34 + l16] = aZ0[j]; xw[(krow*4+j)*34 + 16 + l16] = aZ1[j]; }
    UQ xz_; xz_.u[0] = xz0; xz_.u[1] = xz1;
    float zf[8];
    #pragma unroll
    for (int q = 0; q < 8; ++q) zf[q] = sigm(b2f(xz_.h[q]) + xw[r4 * 34 + cb + q]);
    f32x4 g0 = Z4, g1 = Z4;
    #pragma unroll
    for (int kk = 0; kk < 2; ++kk) {
      bfrag a = *(const bfrag*)&dpan[((kk * 4 + krow) * 16 + l16) * 8];
      g0 = MFMA(a, BG[kk][0], g0); g1 = MFMA(a, BG[kk][1], g1);
    }
    #pragma unroll
    for (int j = 0; j < 4; ++j) { xw[(krow*4+j)*34 + l16] = g0[j]; xw[(krow*4+j)*34 + 16 + l16] = g1[j]; }
    float gm8[8];
    #pragma unroll
    for (int q = 0; q < 8; ++q)
      gm8[q] = __expf(-fmaxf(0.f, xw[r4 * 34 + cb + q] + gb8[q]));
    // ---- hop 2: wait rh all-gather ----
    if (wid == 0) { if (!poll_ge(FB + 16 + (lane & 15), (u32)(t + 1))) s_ab = 1; }
    __syncthreads();
    if (s_ab) break;
    stage_bf16(rpan, RHB + (size_t)m0 * 512, tid, false);
    __syncthreads();
    // ---- h-candidate GEMM (K=512) + blend + publish ----
    f32x4 aH0 = Z4, aH1 = Z4;
    #pragma unroll
    for (int kk = 0; kk < 16; ++kk) {
      bfrag a = *(const bfrag*)&rpan[((kk * 4 + krow) * 16 + l16) * 8];
      aH0 = MFMA(a, BH[kk][0], aH0); aH1 = MFMA(a, BH[kk][1], aH1);
    }
    #pragma unroll
    for (int j = 0; j < 4; ++j) { xw[(krow*4+j)*34 + l16] = aH0[j]; xw[(krow*4+j)*34 + 16 + l16] = aH1[j]; }
    UQ xh_; xh_.u[0] = xh0; xh_.u[1] = xh1;
    UQ hw_, hdn_;
    #pragma unroll
    for (int q = 0; q < 8; ++q) {
      float til = tanh_f(b2f(xh_.h[q]) + xw[r4 * 34 + cb + q]);
      float hn = (1.f - zf[q]) * b2f(hd_.h[q]) + zf[q] * til;
      hw_.h[q] = f2b(hn);
      hdn_.h[q] = f2b(gm8[q] * hn);
    }
    if (t + 1 < NS) {
      u16* hdst = HDECB + (size_t)(m0 + r4) * 512 + cw + cb;
      cstore64(hdst, hdn_.u[0]); cstore64(hdst + 4, hdn_.u[1]);
    }
    asm volatile("s_waitcnt vmcnt(0)" ::: "memory");
    if (lane == 0) cstore32(FB + 0 + pw, (u32)(t + 1));
    // HALL store off critical path; [b][s][h] layout for coalesced attn reads
    u16* hp = HALL + ((size_t)(m0 + r4) * NS + t) * 512 + cw + cb;
    *(u64*)hp = hw_.u[0]; *(u64*)(hp + 4) = hw_.u[1];
    __syncthreads();
  }
}

// ---------------- post kernels ----------------

// HALL is [b][s][h]; all reads coalesced.
__global__ __launch_bounds__(256) void attn_k(const u16* __restrict__ HALL,
                                              const float* __restrict__ av,
                                              float* __restrict__ ATTN){
  const int b = blockIdx.x, tid = threadIdx.x, lane = tid & 63, wid = tid >> 6;
  __shared__ float avs[512], sc[256], wgt[256], red[8];
  for (int i = tid; i < 512; i += 256) avs[i] = av[i];
  __syncthreads();
  const u16* base = HALL + (size_t)b * NS * 512;
  // phase 1: scores — wave w handles 50 rows; 1KB coalesced row reads
  for (int i = 0; i < 50; ++i) {
    const int s = wid * 50 + i;
    UQ w8; w8.q = *(const uint4*)(base + (size_t)s * 512 + lane * 8);
    float p = 0.f;
    #pragma unroll
    for (int j = 0; j < 8; ++j) p += b2f(w8.h[j]) * avs[lane * 8 + j];
    #pragma unroll
    for (int off = 32; off; off >>= 1) p += __shfl_xor(p, off, 64);
    if (lane == 0) sc[s] = p * 0.04419417382415922f;   // 1/sqrt(512)
  }
  __syncthreads();
  // softmax over 200
  float val = (tid < NS) ? sc[tid] : -3.0e38f;
  float m = val;
  #pragma unroll
  for (int off = 32; off; off >>= 1) m = fmaxf(m, __shfl_xor(m, off, 64));
  if (lane == 0) red[wid] = m;
  __syncthreads();
  m = fmaxf(fmaxf(red[0], red[1]), fmaxf(red[2], red[3]));
  float e = (tid < NS) ? __expf(val - m) : 0.f;
  float sum = e;
  #pragma unroll
  for (int off = 32; off; off >>= 1) sum += __shfl_xor(sum, off, 64);
  if (lane == 0) red[4 + wid] = sum;
  __syncthreads();
  const float ssum = red[4] + red[5] + red[6] + red[7];
  wgt[tid] = e / ssum;
  __syncthreads();
  // phase 2: weighted sum — per s, 256 threads read 1KB contiguous
  float a0 = 0.f, a1 = 0.f;
  const int h0 = tid * 2;
  for (int s = 0; s < NS; ++s) {
    const float w = wgt[s];
    u32 pr = *(const u32*)(base + (size_t)s * 512 + h0);
    a0 += w * b2f((u16)(pr & 0xFFFFu));
    a1 += w * b2f((u16)(pr >> 16));
  }
  ATTN[(size_t)b * 512 + h0] = a0;
  ATTN[(size_t)b * 512 + h0 + 1] = a1;
}

// 4 batch rows per WG: WT re-read traffic 256MB -> 64MB
__global__ void out_k(const float* __restrict__ ATTN, const float* __restrict__ Ain,
                      const float* __restrict__ WT, const float* __restrict__ bout,
                      float* __restrict__ OUT){
  const int g = blockIdx.x, tid = threadIdx.x;
  __shared__ float ah[4][520];
  for (int i = tid; i < 4 * 520; i += 256) {
    int bb = i / 520, k = i % 520;
    int b = g * 4 + bb;
    ah[bb][k] = (k < 512) ? ATTN[(size_t)b * 512 + k] : Ain[b * 8 + (k - 512)];
  }
  __syncthreads();
  #pragma unroll
  for (int part = 0; part < 2; ++part) {
    const int ho = part * 256 + tid;
    float a0 = bout[ho], a1 = a0, a2 = a0, a3 = a0;
    for (int k = 0; k < 520; ++k) {
      float w = WT[(size_t)k * 512 + ho];
      a0 += ah[0][k] * w; a1 += ah[1][k] * w; a2 += ah[2][k] * w; a3 += ah[3][k] * w;
    }
    OUT[(size_t)(g * 4 + 0) * 512 + ho] = a0;
    OUT[(size_t)(g * 4 + 1) * 512 + ho] = a1;
    OUT[(size_t)(g * 4 + 2) * 512 + ho] = a2;
    OUT[(size_t)(g * 4 + 3) * 512 + ho] = a3;
  }
}

// ---------------- host ----------------

extern "C" void kernel_launch(void* const* d_in, const int* in_sizes, int n_in,
                              void* d_out, int out_size, void* d_ws, size_t ws_size,
                              hipStream_t stream) {
  (void)in_sizes; (void)n_in; (void)out_size; (void)ws_size;
  const float* x    = (const float*)d_in[0];
  const float* a_in = (const float*)d_in[1];
  const float* tc   = (const float*)d_in[2];
  const float* mask = (const float*)d_in[3];
  const float* wdgx = (const float*)d_in[4];
  const float* bdgx = (const float*)d_in[5];
  const float* Wdgh = (const float*)d_in[6];
  const float* bdgh = (const float*)d_in[7];
  const float* Wm   = (const float*)d_in[8];
  const float* Um   = (const float*)d_in[9];
  const float* Vm   = (const float*)d_in[10];
  const float* bvv  = (const float*)d_in[11];
  const float* attv = (const float*)d_in[12];
  const float* Wout = (const float*)d_in[13];
  const float* bout = (const float*)d_in[14];

  char* ws = (char*)d_ws;
  size_t o = 0;
  auto al = [&](size_t sz) { size_t r = o; o += (sz + 255) & ~(size_t)255; return r; };
  u32*   flags = (u32*)  (ws + al(16 * 32 * 4));
  float* XMEAN = (float*)(ws + al(256));
  float* PX    = (float*)(ws + al((size_t)NS * 64 * 4));
  float* PM    = (float*)(ws + al((size_t)NS * 64 * 4));
  u16*   XHAT  = (u16*)  (ws + al((size_t)NS * NB * 64 * 2));
  u16*   MASKB = (u16*)  (ws + al((size_t)NS * NB * 64 * 2));
  u16*   DELTA = (u16*)  (ws + al((size_t)NS * NB * 64 * 2));
  u16*   HDECB = (u16*)  (ws + al((size_t)NB * NH * 2));
  u16*   RHB   = (u16*)  (ws + al((size_t)NB * NH * 2));
  u16*   XP    = (u16*)  (ws + al((size_t)NS * NB * 1536 * 2));   // 157 MB
  u16*   HALL  = (u16*)  (ws + al((size_t)NS * NB * NH * 2));     // 52 MB
  float* ATTN  = (float*)(ws + al((size_t)NB * NH * 4));
  float* WT    = (float*)(ws + al((size_t)520 * 512 * 4));

  hipMemsetAsync(flags, 0, 16 * 32 * 4, stream);

  transpose_k<<<(520 * 512 + 255) / 256, 256, 0, stream>>>(Wout, WT);
  mean1_k<<<NS, 256, 0, stream>>>(x, mask, PX, PM);
  mean2_k<<<1, 64, 0, stream>>>(PX, PM, XMEAN);
  prep_k<<<NB * ND / 256, 256, 0, stream>>>(x, mask, tc, wdgx, bdgx, XMEAN, XHAT, MASKB, DELTA);
  xpart_k<<<800, 256, 0, stream>>>(Wm, Vm, bvv, XHAT, MASKB, XP);
  grud_rnn<<<64, 256, 0, stream>>>(Um, Wdgh, bdgh, XP, DELTA, HDECB, RHB, HALL, flags);
  attn_k<<<NB, 256, 0, stream>>>(HALL, attv, ATTN);
  out_k<<<64, 256, 0, stream>>>(ATTN, a_in, WT, bout, (float*)d_out);
}

// Round 13
// 1859.639 us; speedup vs baseline: 1.4249x; 1.0065x over previous
//
#include <hip/hip_runtime.h>
#include <hip/hip_bf16.h>
#include <stdint.h>

// GRU-D encoder, MI355X, round 13.
// B=256, S=200, D=64, H=512, TD=8.
// = round 12, with two grud_rnn fixes:
//  (1) transpose scratch stride 34 -> 33 (odd): kills the 4-way LDS bank
//      conflict on epilogue reads (all lanes hit even banks at stride 34).
//  (2) all-lane polls + 2 barriers/step (was 5): every wave polls the flag
//      vector itself and proceeds straight to staging; cross-iteration
//      races are ordered by the FH/FR poll implications (audited).

typedef unsigned short u16;
typedef unsigned int   u32;
typedef unsigned long long u64;
typedef short bfrag  __attribute__((ext_vector_type(8)));
typedef u16   u16x8  __attribute__((ext_vector_type(8)));
typedef float f32x4  __attribute__((ext_vector_type(4)));

#define NB 256
#define NS 200
#define ND 64
#define NH 512

#define MFMA(a,b,c) __builtin_amdgcn_mfma_f32_16x16x32_bf16((a),(b),(c),0,0,0)

union UQ { u16x8 h; bfrag s; u64 u[2]; uint4 q; };

__device__ __forceinline__ float b2f(u16 v){ union { float f; u32 u; } c; c.u = ((u32)v) << 16; return c.f; }
__device__ __forceinline__ u16 f2b(float f){ union { float f; u32 u; } c; c.f = f; u32 r = c.u + 0x7FFFu + ((c.u >> 16) & 1u); return (u16)(r >> 16); }
__device__ __forceinline__ float sigm(float x){ return 1.f / (1.f + __expf(-x)); }
__device__ __forceinline__ float tanh_f(float x){ return 1.f - 2.f / (1.f + __expf(2.f * x)); }

// agent-scope (coherence-point) ops for intra-kernel cross-WG data
__device__ __forceinline__ u64 cload64(const void* p){
  return __hip_atomic_load((const u64*)p, __ATOMIC_RELAXED, __HIP_MEMORY_SCOPE_AGENT);
}
__device__ __forceinline__ void cstore64(void* p, u64 v){
  __hip_atomic_store((u64*)p, v, __ATOMIC_RELAXED, __HIP_MEMORY_SCOPE_AGENT);
}
__device__ __forceinline__ u32 cload32(const u32* p){
  return __hip_atomic_load(p, __ATOMIC_RELAXED, __HIP_MEMORY_SCOPE_AGENT);
}
__device__ __forceinline__ void cstore32(u32* p, u32 v){
  __hip_atomic_store(p, v, __ATOMIC_RELAXED, __HIP_MEMORY_SCOPE_AGENT);
}
// lane-parallel poll with backoff, fuel-bounded (fail fast, no GPU hang)
__device__ __forceinline__ bool poll_ge(const u32* wp, u32 tgt){
  int fuel = 1 << 19;
  while (true) {
    u32 v = cload32(wp);
    if (__all(v >= tgt)) return true;
    __builtin_amdgcn_s_sleep(1);
    if (--fuel == 0) return false;
  }
}
__device__ __forceinline__ bfrag ldfrag(const float* src){
  f32x4 lo = *(const f32x4*)src;
  f32x4 hi = *(const f32x4*)(src + 4);
  UQ z;
  z.h[0]=f2b(lo[0]); z.h[1]=f2b(lo[1]); z.h[2]=f2b(lo[2]); z.h[3]=f2b(lo[3]);
  z.h[4]=f2b(hi[0]); z.h[5]=f2b(hi[1]); z.h[6]=f2b(hi[2]); z.h[7]=f2b(hi[3]);
  return z.s;
}
// cooperative coalesced staging of a [16][512] bf16 block into an A-panel
__device__ __forceinline__ void stage_bf16(u16* dst, const u16* src, int tid, bool zero){
  const int row = tid >> 4, sc = (tid & 15) * 32;
  u16* dp = &dst[((sc >> 3) * 16 + row) * 8];
  if (!zero) {
    const u16* hs = src + (size_t)row * 512 + sc;
    u64 a0 = cload64(hs),      a1 = cload64(hs + 4),  a2 = cload64(hs + 8),  a3 = cload64(hs + 12);
    u64 a4 = cload64(hs + 16), a5 = cload64(hs + 20), a6 = cload64(hs + 24), a7 = cload64(hs + 28);
    *(u64*)(dp)       = a0; *(u64*)(dp + 4)   = a1;
    *(u64*)(dp + 128) = a2; *(u64*)(dp + 132) = a3;
    *(u64*)(dp + 256) = a4; *(u64*)(dp + 260) = a5;
    *(u64*)(dp + 384) = a6; *(u64*)(dp + 388) = a7;
  } else {
    *(u64*)(dp)       = 0; *(u64*)(dp + 4)   = 0;
    *(u64*)(dp + 128) = 0; *(u64*)(dp + 132) = 0;
    *(u64*)(dp + 256) = 0; *(u64*)(dp + 260) = 0;
    *(u64*)(dp + 384) = 0; *(u64*)(dp + 388) = 0;
  }
}

// ---------------- setup kernels ----------------

__global__ void transpose_k(const float* __restrict__ Wout, float* __restrict__ WT){
  int i = blockIdx.x * 256 + threadIdx.x;
  if (i < 520 * 512) { int k = i >> 9, ho = i & 511; WT[i] = Wout[ho * 520 + k]; }
}

__global__ void mean1_k(const float* __restrict__ x, const float* __restrict__ mask,
                        float* __restrict__ PX, float* __restrict__ PM){
  int s = blockIdx.x, tid = threadIdx.x;
  __shared__ float lx[256], lm[256];
  float xa = 0.f, ma = 0.f;
  for (int i = tid; i < NB * ND; i += 256) {
    int b = i >> 6, d = i & 63;
    size_t ix = ((size_t)b * NS + s) * 64 + d;
    float m = mask[ix];
    xa += m * x[ix]; ma += m;
  }
  lx[tid] = xa; lm[tid] = ma;
  __syncthreads();
  if (tid < 64) {
    PX[(size_t)s * 64 + tid] = lx[tid] + lx[tid + 64] + lx[tid + 128] + lx[tid + 192];
    PM[(size_t)s * 64 + tid] = lm[tid] + lm[tid + 64] + lm[tid + 128] + lm[tid + 192];
  }
}

__global__ void mean2_k(const float* __restrict__ PX, const float* __restrict__ PM,
                        float* __restrict__ XMEAN){
  int d = threadIdx.x;
  float sx = 0.f, sm = 0.f;
  for (int s = 0; s < NS; ++s){ sx += PX[s * 64 + d]; sm += PM[s * 64 + d]; }
  XMEAN[d] = sx / fmaxf(sm, 1.f);
}

__global__ void prep_k(const float* __restrict__ x, const float* __restrict__ mask,
                       const float* __restrict__ tc, const float* __restrict__ wdgx,
                       const float* __restrict__ bdgx, const float* __restrict__ XMEAN,
                       u16* __restrict__ XHAT, u16* __restrict__ MASKB, u16* __restrict__ DELTA){
  int g = blockIdx.x * 256 + threadIdx.x;
  int b = g >> 6, d = g & 63;
  float xmean = XMEAN[d], wx = wdgx[d], bx = bdgx[d];
  float xl = 0.f, del = 0.f, tprev = 0.f, mprev = 1.f;
  for (int s = 0; s < NS; ++s){
    float tv = tc[b * NS + s];
    float dtv = (s == 0) ? 0.f : (tv - tprev);
    tprev = tv;
    del = dtv + (1.f - mprev) * del;
    size_t ix = ((size_t)b * NS + s) * 64 + d;
    float m = mask[ix], xv = x[ix];
    float gx = __expf(-fmaxf(0.f, wx * del + bx));
    float xh = m * xv + (1.f - m) * (gx * xl + (1.f - gx) * xmean);
    size_t ox = ((size_t)s * NB + b) * 64 + d;
    XHAT[ox] = f2b(xh); MASKB[ox] = f2b(m); DELTA[ox] = f2b(del);
    xl = m * xv + (1.f - m) * xl;
    mprev = m;
  }
}

// ---------------- XP precompute ----------------
// XP[row][1536] = [x_hat|m](row) @ [W|V]^T + b for all 51200 rows.
// LDS-staged epilogue -> row-contiguous 1536B write runs (full-line HBM writes).
__global__ __launch_bounds__(256, 1) void xpart_k(
    const float* __restrict__ Wm, const float* __restrict__ Vm,
    const float* __restrict__ bv, const u16* __restrict__ XHAT,
    const u16* __restrict__ MASKB, u16* __restrict__ XP){
  const int tid = threadIdx.x, lane = tid & 63, wid = tid >> 6;
  const int l16 = lane & 15, krow = lane >> 4, r4 = lane >> 2, cb = (lane & 3) * 8;
  const int chunk = blockIdx.x >> 1, p = blockIdx.x & 1;
  const int R0 = chunk * 128;
  const int wbasel = wid * 192;            // local col base within this half
  const int wbaseg = p * 768 + wbasel;     // global col base
  __shared__ u16 panel[16 * 16 * 8];
  __shared__ u16 outs[16][768];            // staged output (24 KB)
  __shared__ float xb[4][16 * 33];
  float* xw = xb[wid];
  const f32x4 Z4 = {0.f, 0.f, 0.f, 0.f};

  bfrag BW[12][2], BV2[12][2];
  #pragma unroll
  for (int ct = 0; ct < 12; ++ct)
    #pragma unroll
    for (int kx = 0; kx < 2; ++kx) {
      BW[ct][kx]  = ldfrag(Wm + (size_t)(wbaseg + ct * 16 + l16) * 64 + kx * 32 + krow * 8);
      BV2[ct][kx] = ldfrag(Vm + (size_t)(wbaseg + ct * 16 + l16) * 64 + kx * 32 + krow * 8);
    }
  float bias6[6][8];
  #pragma unroll
  for (int grp = 0; grp < 6; ++grp)
    #pragma unroll
    for (int q = 0; q < 8; ++q) bias6[grp][q] = bv[wbaseg + grp * 32 + cb + q];

  for (int it = 0; it < 8; ++it) {
    const int R = R0 + it * 16;
    { const int kb = tid >> 4, row = tid & 15;
      const u16* sp = (kb < 8 ? XHAT : MASKB) + (size_t)(R + row) * 64 + (kb & 7) * 8;
      *(uint4*)&panel[(kb * 16 + row) * 8] = *(const uint4*)sp; }
    __syncthreads();
    #pragma unroll
    for (int grp = 0; grp < 6; ++grp) {
      f32x4 ac0 = Z4, ac1 = Z4;
      #pragma unroll
      for (int kx = 0; kx < 2; ++kx) {
        bfrag ax = *(const bfrag*)&panel[((kx * 4 + krow) * 16 + l16) * 8];
        ac0 = MFMA(ax, BW[grp*2][kx], ac0); ac1 = MFMA(ax, BW[grp*2+1][kx], ac1);
        bfrag am = *(const bfrag*)&panel[((8 + kx * 4 + krow) * 16 + l16) * 8];
        ac0 = MFMA(am, BV2[grp*2][kx], ac0); ac1 = MFMA(am, BV2[grp*2+1][kx], ac1);
      }
      #pragma unroll
      for (int j = 0; j < 4; ++j) { xw[(krow*4+j)*33 + l16] = ac0[j]; xw[(krow*4+j)*33 + 16 + l16] = ac1[j]; }
      UQ ov;
      #pragma unroll
      for (int q = 0; q < 8; ++q) ov.h[q] = f2b(xw[r4 * 33 + cb + q] + bias6[grp][q]);
      *(u64*)&outs[r4][wbasel + grp * 32 + cb] = ov.u[0];
      *(u64*)&outs[r4][wbasel + grp * 32 + cb + 4] = ov.u[1];
    }
    __syncthreads();
    // cooperative coalesced write: 16 rows x 96 chunks of 16B (1536B runs)
    for (int c = tid; c < 16 * 96; c += 256) {
      const int row = c / 96, ch = c % 96;
      *(uint4*)(XP + (size_t)(R + row) * 1536 + p * 768 + ch * 8) =
          *(const uint4*)&outs[row][ch * 8];
    }
    __syncthreads();
  }
}

// ---------------- persistent recurrent kernel ----------------
// grid = 64 WGs (16 rb x 4 gate WGs), 256 threads (4 waves).
// XCD-colocating map: lid = (bid&7)*8 + (bid>>3); rb = lid>>2; g = lid&3.
// Flags per rb (stride 32 u32): FH[16]@0, FR[16]@16.
// 2 barriers/step; every wave polls the flag vector itself (all 64 lanes).
__global__ __launch_bounds__(256, 1) void grud_rnn(
    const float* __restrict__ Um, const float* __restrict__ Wdg, const float* __restrict__ bdg,
    const u16* __restrict__ XP, const u16* __restrict__ DELTA,
    u16* __restrict__ HDECB, u16* __restrict__ RHB, u16* __restrict__ HALL,
    u32* __restrict__ flags)
{
  const int tid = threadIdx.x, lane = tid & 63, wid = tid >> 6, bid = blockIdx.x;
  const int lid = (bid & 7) * 8 + (bid >> 3);
  const int rb = lid >> 2, g = lid & 3, m0 = rb * 16;
  const int l16 = lane & 15, krow = lane >> 4, r4 = lane >> 2, cb = (lane & 3) * 8;
  const int pw = g * 4 + wid;
  const int cw = g * 128 + wid * 32;
  u32* FB = flags + rb * 32;

  __shared__ u16 hpan[64 * 16 * 8];
  __shared__ u16 rpan[64 * 16 * 8];
  __shared__ u16 dpan[8 * 16 * 8];
  __shared__ float xb[4][16 * 33];
  __shared__ int s_ab;
  float* xw = xb[wid];
  const f32x4 Z4 = {0.f, 0.f, 0.f, 0.f};
  if (tid == 0) s_ab = 0;
  __syncthreads();

  bfrag BZ[16][2], BR[16][2], BH[16][2], BG[2][2];
  #pragma unroll
  for (int kk = 0; kk < 16; ++kk) {
    const size_t ko = (size_t)(kk * 32 + krow * 8);
    #pragma unroll
    for (int t2 = 0; t2 < 2; ++t2) {
      BZ[kk][t2] = ldfrag(Um + (size_t)(       cw + t2 * 16 + l16) * 512 + ko);
      BR[kk][t2] = ldfrag(Um + (size_t)(512  + cw + t2 * 16 + l16) * 512 + ko);
      BH[kk][t2] = ldfrag(Um + (size_t)(1024 + cw + t2 * 16 + l16) * 512 + ko);
    }
  }
  #pragma unroll
  for (int kk = 0; kk < 2; ++kk)
    #pragma unroll
    for (int t2 = 0; t2 < 2; ++t2)
      BG[kk][t2] = ldfrag(Wdg + (size_t)(cw + t2 * 16 + l16) * 64 + kk * 32 + krow * 8);
  float gb8[8];
  #pragma unroll
  for (int q = 0; q < 8; ++q) gb8[q] = bdg[cw + cb + q];

  const int slot = ((cw + cb) >> 3) * 16 + r4;

  for (int t = 0; t < NS; ++t) {
    const int tn = (t + 1 < NS) ? t + 1 : NS - 1;
    // static per-t loads before the poll (plain cached)
    const u16* xp = XP + ((size_t)t * NB + m0 + r4) * 1536 + cw + cb;
    u64 xz0 = *(const u64*)(xp),        xz1 = *(const u64*)(xp + 4);
    u64 xr0 = *(const u64*)(xp + 512),  xr1 = *(const u64*)(xp + 516);
    u64 xh0 = *(const u64*)(xp + 1024), xh1 = *(const u64*)(xp + 1028);
    // ---- hop 1: every wave polls FH itself, then stages immediately ----
    if (t > 0) { if (!poll_ge(FB + (lane & 15), (u32)t)) s_ab = 1; }
    stage_bf16(hpan, HDECB + (size_t)m0 * 512, tid, t == 0);
    if (tid < 128) {   // dpan: static delta(t+1); safe post-poll (audited)
      const int kb = tid >> 4, row = tid & 15;
      const u16* sp = DELTA + ((size_t)tn * NB + m0 + row) * 64 + kb * 8;
      *(uint4*)&dpan[(kb * 16 + row) * 8] = *(const uint4*)sp;
    }
    __syncthreads();                          // B1
    if (s_ab) break;
    // ---- r GEMM (K=512) ----
    f32x4 aR0 = Z4, aR1 = Z4;
    #pragma unroll
    for (int kk = 0; kk < 16; ++kk) {
      bfrag a = *(const bfrag*)&hpan[((kk * 4 + krow) * 16 + l16) * 8];
      aR0 = MFMA(a, BR[kk][0], aR0); aR1 = MFMA(a, BR[kk][1], aR1);
    }
    #pragma unroll
    for (int j = 0; j < 4; ++j) { xw[(krow*4+j)*33 + l16] = aR0[j]; xw[(krow*4+j)*33 + 16 + l16] = aR1[j]; }
    UQ hd_; hd_.h = *(const u16x8*)&hpan[slot * 8];
    UQ xr_; xr_.u[0] = xr0; xr_.u[1] = xr1;
    UQ rh_;
    #pragma unroll
    for (int q = 0; q < 8; ++q) {
      float rv = sigm(b2f(xr_.h[q]) + xw[r4 * 33 + cb + q]);
      rh_.h[q] = f2b(rv * b2f(hd_.h[q]));
    }
    u16* rdst = RHB + (size_t)(m0 + r4) * 512 + cw + cb;
    cstore64(rdst, rh_.u[0]); cstore64(rdst + 4, rh_.u[1]);
    asm volatile("s_waitcnt vmcnt(0)" ::: "memory");
    if (lane == 0) cstore32(FB + 16 + pw, (u32)(t + 1));
    // ---- z GEMM + gamma GEMM fill the rh round-trip window ----
    f32x4 aZ0 = Z4, aZ1 = Z4;
    #pragma unroll
    for (int kk = 0; kk < 16; ++kk) {
      bfrag a = *(const bfrag*)&hpan[((kk * 4 + krow) * 16 + l16) * 8];
      aZ0 = MFMA(a, BZ[kk][0], aZ0); aZ1 = MFMA(a, BZ[kk][1], aZ1);
    }
    #pragma unroll
    for (int j = 0; j < 4; ++j) { xw[(krow*4+j)*33 + l16] = aZ0[j]; xw[(krow*4+j)*33 + 16 + l16] = aZ1[j]; }
    UQ xz_; xz_.u[0] = xz0; xz_.u[1] = xz1;
    float zf[8];
    #pragma unroll
    for (int q = 0; q < 8; ++q) zf[q] = sigm(b2f(xz_.h[q]) + xw[r4 * 33 + cb + q]);
    f32x4 g0 = Z4, g1 = Z4;
    #pragma unroll
    for (int kk = 0; kk < 2; ++kk) {
      bfrag a = *(const bfrag*)&dpan[((kk * 4 + krow) * 16 + l16) * 8];
      g0 = MFMA(a, BG[kk][0], g0); g1 = MFMA(a, BG[kk][1], g1);
    }
    #pragma unroll
    for (int j = 0; j < 4; ++j) { xw[(krow*4+j)*33 + l16] = g0[j]; xw[(krow*4+j)*33 + 16 + l16] = g1[j]; }
    float gm8[8];
    #pragma unroll
    for (int q = 0; q < 8; ++q)
      gm8[q] = __expf(-fmaxf(0.f, xw[r4 * 33 + cb + q] + gb8[q]));
    // ---- hop 2: every wave polls FR itself, stages rpan ----
    if (!poll_ge(FB + 16 + (lane & 15), (u32)(t + 1))) s_ab = 1;
    stage_bf16(rpan, RHB + (size_t)m0 * 512, tid, false);
    __syncthreads();                          // B2
    if (s_ab) break;
    // ---- h-candidate GEMM (K=512) + blend + publish ----
    f32x4 aH0 = Z4, aH1 = Z4;
    #pragma unroll
    for (int kk = 0; kk < 16; ++kk) {
      bfrag a = *(const bfrag*)&rpan[((kk * 4 + krow) * 16 + l16) * 8];
      aH0 = MFMA(a, BH[kk][0], aH0); aH1 = MFMA(a, BH[kk][1], aH1);
    }
    #pragma unroll
    for (int j = 0; j < 4; ++j) { xw[(krow*4+j)*33 + l16] = aH0[j]; xw[(krow*4+j)*33 + 16 + l16] = aH1[j]; }
    UQ xh_; xh_.u[0] = xh0; xh_.u[1] = xh1;
    UQ hw_, hdn_;
    #pragma unroll
    for (int q = 0; q < 8; ++q) {
      float til = tanh_f(b2f(xh_.h[q]) + xw[r4 * 33 + cb + q]);
      float hn = (1.f - zf[q]) * b2f(hd_.h[q]) + zf[q] * til;
      hw_.h[q] = f2b(hn);
      hdn_.h[q] = f2b(gm8[q] * hn);
    }
    if (t + 1 < NS) {
      u16* hdst = HDECB + (size_t)(m0 + r4) * 512 + cw + cb;
      cstore64(hdst, hdn_.u[0]); cstore64(hdst + 4, hdn_.u[1]);
    }
    asm volatile("s_waitcnt vmcnt(0)" ::: "memory");
    if (lane == 0) cstore32(FB + 0 + pw, (u32)(t + 1));
    // HALL store off critical path; [b][s][h] layout for coalesced attn reads
    u16* hp = HALL + ((size_t)(m0 + r4) * NS + t) * 512 + cw + cb;
    *(u64*)hp = hw_.u[0]; *(u64*)(hp + 4) = hw_.u[1];
    // no end barrier: next-iter hpan/rpan/dpan staging is ordered by the
    // FH/FR polls (publisher count implies all reads of this iter are done)
  }
}

// ---------------- post kernels ----------------

// HALL is [b][s][h]; all reads coalesced.
__global__ __launch_bounds__(256) void attn_k(const u16* __restrict__ HALL,
                                              const float* __restrict__ av,
                                              float* __restrict__ ATTN){
  const int b = blockIdx.x, tid = threadIdx.x, lane = tid & 63, wid = tid >> 6;
  __shared__ float avs[512], sc[256], wgt[256], red[8];
  for (int i = tid; i < 512; i += 256) avs[i] = av[i];
  __syncthreads();
  const u16* base = HALL + (size_t)b * NS * 512;
  for (int i = 0; i < 50; ++i) {
    const int s = wid * 50 + i;
    UQ w8; w8.q = *(const uint4*)(base + (size_t)s * 512 + lane * 8);
    float p = 0.f;
    #pragma unroll
    for (int j = 0; j < 8; ++j) p += b2f(w8.h[j]) * avs[lane * 8 + j];
    #pragma unroll
    for (int off = 32; off; off >>= 1) p += __shfl_xor(p, off, 64);
    if (lane == 0) sc[s] = p * 0.04419417382415922f;   // 1/sqrt(512)
  }
  __syncthreads();
  float val = (tid < NS) ? sc[tid] : -3.0e38f;
  float m = val;
  #pragma unroll
  for (int off = 32; off; off >>= 1) m = fmaxf(m, __shfl_xor(m, off, 64));
  if (lane == 0) red[wid] = m;
  __syncthreads();
  m = fmaxf(fmaxf(red[0], red[1]), fmaxf(red[2], red[3]));
  float e = (tid < NS) ? __expf(val - m) : 0.f;
  float sum = e;
  #pragma unroll
  for (int off = 32; off; off >>= 1) sum += __shfl_xor(sum, off, 64);
  if (lane == 0) red[4 + wid] = sum;
  __syncthreads();
  const float ssum = red[4] + red[5] + red[6] + red[7];
  wgt[tid] = e / ssum;
  __syncthreads();
  float a0 = 0.f, a1 = 0.f;
  const int h0 = tid * 2;
  for (int s = 0; s < NS; ++s) {
    const float w = wgt[s];
    u32 pr = *(const u32*)(base + (size_t)s * 512 + h0);
    a0 += w * b2f((u16)(pr & 0xFFFFu));
    a1 += w * b2f((u16)(pr >> 16));
  }
  ATTN[(size_t)b * 512 + h0] = a0;
  ATTN[(size_t)b * 512 + h0 + 1] = a1;
}

// 4 batch rows per WG: WT re-read traffic 256MB -> 64MB
__global__ void out_k(const float* __restrict__ ATTN, const float* __restrict__ Ain,
                      const float* __restrict__ WT, const float* __restrict__ bout,
                      float* __restrict__ OUT){
  const int g = blockIdx.x, tid = threadIdx.x;
  __shared__ float ah[4][520];
  for (int i = tid; i < 4 * 520; i += 256) {
    int bb = i / 520, k = i % 520;
    int b = g * 4 + bb;
    ah[bb][k] = (k < 512) ? ATTN[(size_t)b * 512 + k] : Ain[b * 8 + (k - 512)];
  }
  __syncthreads();
  #pragma unroll
  for (int part = 0; part < 2; ++part) {
    const int ho = part * 256 + tid;
    float a0 = bout[ho], a1 = a0, a2 = a0, a3 = a0;
    for (int k = 0; k < 520; ++k) {
      float w = WT[(size_t)k * 512 + ho];
      a0 += ah[0][k] * w; a1 += ah[1][k] * w; a2 += ah[2][k] * w; a3 += ah[3][k] * w;
    }
    OUT[(size_t)(g * 4 + 0) * 512 + ho] = a0;
    OUT[(size_t)(g * 4 + 1) * 512 + ho] = a1;
    OUT[(size_t)(g * 4 + 2) * 512 + ho] = a2;
    OUT[(size_t)(g * 4 + 3) * 512 + ho] = a3;
  }
}

// ---------------- host ----------------

extern "C" void kernel_launch(void* const* d_in, const int* in_sizes, int n_in,
                              void* d_out, int out_size, void* d_ws, size_t ws_size,
                              hipStream_t stream) {
  (void)in_sizes; (void)n_in; (void)out_size; (void)ws_size;
  const float* x    = (const float*)d_in[0];
  const float* a_in = (const float*)d_in[1];
  const float* tc   = (const float*)d_in[2];
  const float* mask = (const float*)d_in[3];
  const float* wdgx = (const float*)d_in[4];
  const float* bdgx = (const float*)d_in[5];
  const float* Wdgh = (const float*)d_in[6];
  const float* bdgh = (const float*)d_in[7];
  const float* Wm   = (const float*)d_in[8];
  const float* Um   = (const float*)d_in[9];
  const float* Vm   = (const float*)d_in[10];
  const float* bvv  = (const float*)d_in[11];
  const float* attv = (const float*)d_in[12];
  const float* Wout = (const float*)d_in[13];
  const float* bout = (const float*)d_in[14];

  char* ws = (char*)d_ws;
  size_t o = 0;
  auto al = [&](size_t sz) { size_t r = o; o += (sz + 255) & ~(size_t)255; return r; };
  u32*   flags = (u32*)  (ws + al(16 * 32 * 4));
  float* XMEAN = (float*)(ws + al(256));
  float* PX    = (float*)(ws + al((size_t)NS * 64 * 4));
  float* PM    = (float*)(ws + al((size_t)NS * 64 * 4));
  u16*   XHAT  = (u16*)  (ws + al((size_t)NS * NB * 64 * 2));
  u16*   MASKB = (u16*)  (ws + al((size_t)NS * NB * 64 * 2));
  u16*   DELTA = (u16*)  (ws + al((size_t)NS * NB * 64 * 2));
  u16*   HDECB = (u16*)  (ws + al((size_t)NB * NH * 2));
  u16*   RHB   = (u16*)  (ws + al((size_t)NB * NH * 2));
  u16*   XP    = (u16*)  (ws + al((size_t)NS * NB * 1536 * 2));   // 157 MB
  u16*   HALL  = (u16*)  (ws + al((size_t)NS * NB * NH * 2));     // 52 MB
  float* ATTN  = (float*)(ws + al((size_t)NB * NH * 4));
  float* WT    = (float*)(ws + al((size_t)520 * 512 * 4));

  hipMemsetAsync(flags, 0, 16 * 32 * 4, stream);

  transpose_k<<<(520 * 512 + 255) / 256, 256, 0, stream>>>(Wout, WT);
  mean1_k<<<NS, 256, 0, stream>>>(x, mask, PX, PM);
  mean2_k<<<1, 64, 0, stream>>>(PX, PM, XMEAN);
  prep_k<<<NB * ND / 256, 256, 0, stream>>>(x, mask, tc, wdgx, bdgx, XMEAN, XHAT, MASKB, DELTA);
  xpart_k<<<800, 256, 0, stream>>>(Wm, Vm, bvv, XHAT, MASKB, XP);
  grud_rnn<<<64, 256, 0, stream>>>(Um, Wdgh, bdgh, XP, DELTA, HDECB, RHB, HALL, flags);
  attn_k<<<NB, 256, 0, stream>>>(HALL, attv, ATTN);
  out_k<<<64, 256, 0, stream>>>(ATTN, a_in, WT, bout, (float*)d_out);
}